// Round 12
// baseline (174.642 us; speedup 1.0000x reference)
//
#include <hip/hip_runtime.h>
#include <hip/hip_bf16.h>

#define NT 4096
#define HD 64
#define CCH 128
#define LOG2E 1.4426950408889634f
#define QK_SCALE 0.08838834764831845f      // 128^-0.5 (reference scales by C)
#define QSCALE_LOG2 (QK_SCALE * LOG2E)     // folded so softmax uses exp2 directly

typedef __attribute__((ext_vector_type(8))) short short8;   // 8 bf16 (4 VGPR)
typedef __attribute__((ext_vector_type(4))) float f32x4;

__device__ __forceinline__ float4 ld4(const float* p) {
    return *reinterpret_cast<const float4*>(p);
}

__device__ __forceinline__ unsigned short f2bf(float f) {  // RNE float->bf16
    union { float f; unsigned u; } v; v.f = f;
    unsigned r = v.u + 0x7fff + ((v.u >> 16) & 1);
    return (unsigned short)(r >> 16);
}

__device__ __forceinline__ unsigned pkbf(float a, float b) {  // pack 2 bf16 (RNE)
    __hip_bfloat162 h = __float22bfloat162_rn(make_float2(a, b));
    return *reinterpret_cast<unsigned*>(&h);
}

__device__ __forceinline__ float exp2fast(float x) {
#if __has_builtin(__builtin_amdgcn_exp2f)
    return __builtin_amdgcn_exp2f(x);
#else
    return exp2f(x);
#endif
}

// ---------------- Kernel 1: QKV projection, bf16 MFMA (validated r11) ----------
__global__ __launch_bounds__(256) void k_qkv(const float* __restrict__ x,
                                             const float* __restrict__ wqkv,
                                             unsigned short* __restrict__ Qb,
                                             unsigned short* __restrict__ Kb,
                                             unsigned short* __restrict__ Vt) {
    __shared__ __align__(16) unsigned short xs[64][128];
    __shared__ __align__(16) unsigned short wt[64][128];
    const int t  = threadIdx.x;
    const int mt = blockIdx.x;
    const int nt = blockIdx.y;

    {
        const int r = t >> 2, qd = t & 3;
        const float* src = &x[(size_t)(mt * 64 + r) * CCH + qd * 32];
        unsigned pk[16];
        #pragma unroll
        for (int i = 0; i < 8; ++i) {
            float4 v = ld4(src + i * 4);
            pk[2 * i]     = pkbf(v.x, v.y);
            pk[2 * i + 1] = pkbf(v.z, v.w);
        }
        #pragma unroll
        for (int g2 = 0; g2 < 4; ++g2) {
            const int gp = (qd * 4 + g2) ^ (r & 7);
            *reinterpret_cast<uint4*>(&xs[r][gp * 8]) =
                make_uint4(pk[4 * g2], pk[4 * g2 + 1], pk[4 * g2 + 2], pk[4 * g2 + 3]);
        }
    }
    {
        const int g  = t >> 4;
        const int j4 = (t & 15) * 4;
        float4 col[8];
        #pragma unroll
        for (int kk = 0; kk < 8; ++kk)
            col[kk] = ld4(&wqkv[(size_t)(g * 8 + kk) * 384 + nt * 64 + j4]);
        const float* c = reinterpret_cast<const float*>(col);
        #pragma unroll
        for (int jj = 0; jj < 4; ++jj) {
            const int j = j4 + jj;
            unsigned a0 = pkbf(c[0 * 4 + jj], c[1 * 4 + jj]);
            unsigned a1 = pkbf(c[2 * 4 + jj], c[3 * 4 + jj]);
            unsigned a2 = pkbf(c[4 * 4 + jj], c[5 * 4 + jj]);
            unsigned a3 = pkbf(c[6 * 4 + jj], c[7 * 4 + jj]);
            *reinterpret_cast<uint4*>(&wt[j][(g ^ (j & 7)) * 8]) = make_uint4(a0, a1, a2, a3);
        }
    }
    __syncthreads();

    const int lane = t & 63, w = t >> 6, q = lane & 15, Lw = lane >> 4;

    short8 qa4[4];
    #pragma unroll
    for (int ks = 0; ks < 4; ++ks)
        qa4[ks] = *reinterpret_cast<const short8*>(
            &xs[w * 16 + q][((Lw + 4 * ks) ^ (q & 7)) * 8]);

    f32x4 acc[4];
    #pragma unroll
    for (int ct = 0; ct < 4; ++ct) acc[ct] = (f32x4)0.f;
    #pragma unroll
    for (int ct = 0; ct < 4; ++ct) {
        const int j = ct * 16 + q;
        #pragma unroll
        for (int ks = 0; ks < 4; ++ks) {
            short8 wb = *reinterpret_cast<const short8*>(
                &wt[j][((Lw + 4 * ks) ^ (j & 7)) * 8]);
            acc[ct] = __builtin_amdgcn_mfma_f32_16x16x32_bf16(qa4[ks], wb, acc[ct], 0, 0, 0);
        }
    }

    const int head  = nt / 3;
    const int which = nt - 3 * head;
    const int gi0 = mt * 64 + w * 16 + Lw * 4;
    const int bb  = gi0 >> 12;
    const int n0  = gi0 & 4095;
    const int bhh = bb * 2 + head;

    if (which == 0) {
        #pragma unroll
        for (int ct = 0; ct < 4; ++ct) {
            const int d = ct * 16 + q;
            #pragma unroll
            for (int r = 0; r < 4; ++r)
                Qb[((size_t)(bhh * NT + n0 + r)) * HD + d] = f2bf(acc[ct][r] * QSCALE_LOG2);
        }
    } else if (which == 1) {
        #pragma unroll
        for (int ct = 0; ct < 4; ++ct) {
            const int d = ct * 16 + q;
            #pragma unroll
            for (int r = 0; r < 4; ++r)
                Kb[((size_t)(bhh * NT + n0 + r)) * HD + d] = f2bf(acc[ct][r]);
        }
    } else {
        #pragma unroll
        for (int ct = 0; ct < 4; ++ct) {
            const int d = ct * 16 + q;
            uint2 u;
            u.x = pkbf(acc[ct][0], acc[ct][1]);
            u.y = pkbf(acc[ct][2], acc[ct][3]);
            *reinterpret_cast<uint2*>(&Vt[((size_t)(bhh * HD + d)) * NT + n0]) = u;
        }
    }
}

// ---------------- Kernel 2: flash attention, j-split occupancy x2 ----------------
// grid (128, 8), 256 thr. Block = 32 q-rows. Wave w: rh=w>>1 picks 16-row half,
// p=w&1 picks j in [p*32, p*32+32) of each 64-wide KV tile (split-K with private
// m/l/O, merged via LDS at the end). 4 blocks/CU -> 16 waves/CU (was 8).
// P strip: 16 rows x 80B, rotation swizzle (g+q)&3. T13 defer-rescale (THR=8 log2).
__global__ __launch_bounds__(256) void k_attn(const unsigned short* __restrict__ Qb,
                                              const unsigned short* __restrict__ Kb,
                                              const unsigned short* __restrict__ Vt,
                                              float* __restrict__ R) {
    __shared__ __align__(16) char smem[37888];
    char* Ks0 = smem;              // [8192]
    char* Ks1 = smem + 8192;
    char* Vs0 = smem + 16384;
    char* Vs1 = smem + 24576;
    char* PwA = smem + 32768;      // 4 waves x 1280

    const int t    = threadIdx.x;
    const int lane = t & 63;
    const int w    = t >> 6;
    const int rh   = w >> 1;       // row-half
    const int p    = w & 1;        // j-parity
    const int qt   = blockIdx.x;   // 32 rows each
    const int bh   = blockIdx.y;

    const char* KbT = (const char*)Kb + (size_t)bh * NT * HD * 2;
    const char* VtT = (const char*)Vt + (size_t)bh * HD * NT * 2;

    const int q  = lane & 15;
    const int Lw = lane >> 4;

    short8 qa[2];
    {
        const int qrow = qt * 32 + rh * 16 + q;
        const char* qp = (const char*)Qb +
            (((size_t)bh * NT + qrow) * HD + (Lw * 8)) * 2;
        qa[0] = *reinterpret_cast<const short8*>(qp);
        qa[1] = *reinterpret_cast<const short8*>(qp + 64);
    }

    char* Prow = PwA + w * 1280 + q * 80;

    float mrow = -1e30f, lrow = 0.f;
    f32x4 oacc[4];
    #pragma unroll
    for (int i = 0; i < 4; ++i) oacc[i] = (f32x4)0.f;

    const int rc0 = t >> 3;
    const int sp  = t & 7;
    const int rc1 = rc0 + 32;

    const char* kp0 = KbT + rc0 * 128 + (sp ^ (rc0 & 7)) * 16;
    const char* kp1 = KbT + rc1 * 128 + (sp ^ (rc1 & 7)) * 16;
    const char* vp0 = VtT + (size_t)rc0 * 8192 + (sp ^ (rc0 & 7)) * 16;
    const char* vp1 = VtT + (size_t)rc1 * 8192 + (sp ^ (rc1 & 7)) * 16;

    auto gll = [](const char* g, char* l) {
        __builtin_amdgcn_global_load_lds(
            (const __attribute__((address_space(1))) void*)g,
            (__attribute__((address_space(3))) void*)l, 16, 0, 0);
    };
    auto stage = [&](char* KsD, char* VsD) {
        gll(kp0, KsD + t * 16); gll(kp1, KsD + 4096 + t * 16);
        gll(vp0, VsD + t * 16); gll(vp1, VsD + 4096 + t * 16);
        kp0 += 8192; kp1 += 8192; vp0 += 128; vp1 += 128;
    };

    auto compute = [&](const char* KsC, const char* VsC) {
        // S^T for our 32 j's: ct = 2p + c
        f32x4 sacc[2];
        sacc[0] = (f32x4)0.f; sacc[1] = (f32x4)0.f;
        #pragma unroll
        for (int c = 0; c < 2; ++c) {
            const int j = (2 * p + c) * 16 + q;
            #pragma unroll
            for (int ks = 0; ks < 2; ++ks) {
                const int slot = (Lw + 4 * ks) ^ (lane & 7);
                short8 kb = *reinterpret_cast<const short8*>(KsC + j * 128 + slot * 16);
                sacc[c] = __builtin_amdgcn_mfma_f32_16x16x32_bf16(kb, qa[ks], sacc[c], 0, 0, 0);
            }
        }
        // online softmax over 32 j's (8 in-reg + 4-lane group), exp2 domain
        float mx = -1e30f;
        #pragma unroll
        for (int c = 0; c < 2; ++c)
            #pragma unroll
            for (int r = 0; r < 4; ++r) mx = fmaxf(mx, sacc[c][r]);
        mx = fmaxf(mx, __shfl_xor(mx, 16));
        mx = fmaxf(mx, __shfl_xor(mx, 32));
        // T13 defer-rescale: skip when max grew by <= 8 (P bounded by 2^8)
        if (!__all(mx <= mrow + 8.0f)) {
            const float mn = fmaxf(mrow, mx);
            const float corr = exp2fast(mrow - mn);
            mrow = mn;
            lrow *= corr;
            #pragma unroll
            for (int dt = 0; dt < 4; ++dt) oacc[dt] *= corr;
        }
        float e[2][4];
        float sum = 0.f;
        #pragma unroll
        for (int c = 0; c < 2; ++c)
            #pragma unroll
            for (int r = 0; r < 4; ++r) {
                float ev = exp2fast(sacc[c][r] - mrow);
                e[c][r] = ev;
                sum += ev;
            }
        sum += __shfl_xor(sum, 16);
        sum += __shfl_xor(sum, 32);
        lrow += sum;

        // P[q][j-local] -> 80B strip rows, rotation (g+q)&3
        #pragma unroll
        for (int c = 0; c < 2; ++c) {
            const int g = 2 * c + (Lw >> 1);
            uint2 u = make_uint2(pkbf(e[c][0], e[c][1]), pkbf(e[c][2], e[c][3]));
            *reinterpret_cast<uint2*>(Prow + (((g + q) & 3) << 4) + ((Lw & 1) << 3)) = u;
        }
        short8 pb = *reinterpret_cast<const short8*>(Prow + (((Lw + q) & 3) << 4));

        // O^T += V^T P^T over our 32 j's (single k-step)
        #pragma unroll
        for (int dt = 0; dt < 4; ++dt) {
            const int d = dt * 16 + q;
            const int slot = (4 * p + Lw) ^ (lane & 7);
            short8 vb = *reinterpret_cast<const short8*>(VsC + d * 128 + slot * 16);
            oacc[dt] = __builtin_amdgcn_mfma_f32_16x16x32_bf16(vb, pb, oacc[dt], 0, 0, 0);
        }
    };

    stage(Ks0, Vs0);
    __syncthreads();
    for (int it = 0; it < 32; ++it) {
        stage(Ks1, Vs1);
        compute(Ks0, Vs0);
        __syncthreads();
        if (it < 31) stage(Ks0, Vs0);
        compute(Ks1, Vs1);
        __syncthreads();
    }

    // ---- merge the two j-halves (p=1 -> LDS, p=0 merges + stores) ----
    if (p) {
        float* dst = reinterpret_cast<float*>(smem) + (rh * 64 + lane) * 18;
        #pragma unroll
        for (int dt = 0; dt < 4; ++dt)
            #pragma unroll
            for (int r = 0; r < 4; ++r) dst[dt * 4 + r] = oacc[dt][r];
        dst[16] = mrow; dst[17] = lrow;
    }
    __syncthreads();
    if (!p) {
        const float* src = reinterpret_cast<const float*>(smem) + (rh * 64 + lane) * 18;
        const float m1 = src[16], l1 = src[17];
        const float m  = fmaxf(mrow, m1);
        const float c0 = exp2fast(mrow - m);
        const float c1 = exp2fast(m1 - m);
        const float inv = 1.0f / (lrow * c0 + l1 * c1);
        const int b = bh >> 1, h = bh & 1;
        const int row = qt * 32 + rh * 16 + q;
        float* dst = &R[((size_t)(b * NT + row)) * CCH + h * HD];
        #pragma unroll
        for (int dt = 0; dt < 4; ++dt) {
            float4 v;
            v.x = (oacc[dt][0] * c0 + src[dt * 4 + 0] * c1) * inv;
            v.y = (oacc[dt][1] * c0 + src[dt * 4 + 1] * c1) * inv;
            v.z = (oacc[dt][2] * c0 + src[dt * 4 + 2] * c1) * inv;
            v.w = (oacc[dt][3] * c0 + src[dt * 4 + 3] * c1) * inv;
            *reinterpret_cast<float4*>(&dst[dt * 16 + Lw * 4]) = v;
        }
    }
}

// ---------------- Kernel 3: output projection + bias (fp32) ----------------
__global__ __launch_bounds__(256) void k_out(const float* __restrict__ R,
                                             const float* __restrict__ wout,
                                             const float* __restrict__ bout,
                                             float* __restrict__ out) {
    __shared__ float xs[64][132];
    __shared__ float ws[128][68];
    const int t  = threadIdx.x;
    const int mt = blockIdx.x;
    const int nt = blockIdx.y;

    #pragma unroll
    for (int f = 0; f < 8; ++f) {
        int g = f * 256 + t;
        int r = g >> 5, c = (g & 31) << 2;
        *reinterpret_cast<float4*>(&xs[r][c]) = ld4(&R[(mt * 64 + r) * CCH + c]);
    }
    #pragma unroll
    for (int f = 0; f < 8; ++f) {
        int g = f * 256 + t;
        int r = g >> 4, c = (g & 15) << 2;
        *reinterpret_cast<float4*>(&ws[r][c]) = ld4(&wout[r * CCH + nt * 64 + c]);
    }
    __syncthreads();

    const int r0 = (t >> 4) << 2;
    const int c0 = (t & 15) << 2;
    float acc[4][4] = {};
    #pragma unroll 8
    for (int k4 = 0; k4 < 32; ++k4) {
        float a[4][4], b[4][4];
        #pragma unroll
        for (int i = 0; i < 4; ++i) {
            float4 v = ld4(&xs[r0 + i][k4 * 4]);
            a[i][0] = v.x; a[i][1] = v.y; a[i][2] = v.z; a[i][3] = v.w;
        }
        #pragma unroll
        for (int kk = 0; kk < 4; ++kk) {
            float4 v = ld4(&ws[k4 * 4 + kk][c0]);
            b[kk][0] = v.x; b[kk][1] = v.y; b[kk][2] = v.z; b[kk][3] = v.w;
        }
        #pragma unroll
        for (int i = 0; i < 4; ++i)
            #pragma unroll
            for (int kk = 0; kk < 4; ++kk)
                #pragma unroll
                for (int j = 0; j < 4; ++j)
                    acc[i][j] += a[i][kk] * b[kk][j];
    }

    float4 bias = ld4(&bout[nt * 64 + c0]);
    #pragma unroll
    for (int i = 0; i < 4; ++i) {
        int gi = mt * 64 + r0 + i;
        float4 v = make_float4(acc[i][0] + bias.x, acc[i][1] + bias.y,
                               acc[i][2] + bias.z, acc[i][3] + bias.w);
        *reinterpret_cast<float4*>(&out[(size_t)gi * CCH + nt * 64 + c0]) = v;
    }
}

extern "C" void kernel_launch(void* const* d_in, const int* in_sizes, int n_in,
                              void* d_out, int out_size, void* d_ws, size_t ws_size,
                              hipStream_t stream) {
    const float* x    = (const float*)d_in[0];
    const float* wqkv = (const float*)d_in[1];
    const float* wout = (const float*)d_in[2];
    const float* bout = (const float*)d_in[3];
    float* out = (float*)d_out;

    // workspace: Qb/Kb/Vt bf16 (4MB each), R fp32 (8MB) = 20MB
    unsigned short* Qb = (unsigned short*)d_ws;
    unsigned short* Kb = Qb + 2097152;
    unsigned short* Vt = Kb + 2097152;
    float* R = (float*)((char*)d_ws + 12 * 1024 * 1024);

    k_qkv<<<dim3(256, 6), 256, 0, stream>>>(x, wqkv, Qb, Kb, Vt);
    k_attn<<<dim3(128, 8), 256, 0, stream>>>(Qb, Kb, Vt, R);
    k_out<<<dim3(256, 2), 256, 0, stream>>>(R, wout, bout, out);
}

// Round 13
// 152.171 us; speedup vs baseline: 1.1477x; 1.1477x over previous
//
#include <hip/hip_runtime.h>
#include <hip/hip_bf16.h>

#define NT 4096
#define HD 64
#define CCH 128
#define LOG2E 1.4426950408889634f
#define QK_SCALE 0.08838834764831845f      // 128^-0.5 (reference scales by C)
#define QSCALE_LOG2 (QK_SCALE * LOG2E)     // folded so softmax uses exp2 directly

typedef __attribute__((ext_vector_type(8))) short short8;   // 8 bf16 (4 VGPR)
typedef __attribute__((ext_vector_type(4))) float f32x4;

__device__ __forceinline__ float4 ld4(const float* p) {
    return *reinterpret_cast<const float4*>(p);
}

__device__ __forceinline__ unsigned short f2bf(float f) {  // RNE float->bf16
    union { float f; unsigned u; } v; v.f = f;
    unsigned r = v.u + 0x7fff + ((v.u >> 16) & 1);
    return (unsigned short)(r >> 16);
}

__device__ __forceinline__ unsigned pkbf(float a, float b) {  // pack 2 bf16 (RNE)
    __hip_bfloat162 h = __float22bfloat162_rn(make_float2(a, b));
    return *reinterpret_cast<unsigned*>(&h);
}

__device__ __forceinline__ float exp2fast(float x) {
#if __has_builtin(__builtin_amdgcn_exp2f)
    return __builtin_amdgcn_exp2f(x);
#else
    return exp2f(x);
#endif
}

// ---------------- Kernel 1: QKV projection, bf16 MFMA (validated r11) ----------
__global__ __launch_bounds__(256) void k_qkv(const float* __restrict__ x,
                                             const float* __restrict__ wqkv,
                                             unsigned short* __restrict__ Qb,
                                             unsigned short* __restrict__ Kb,
                                             unsigned short* __restrict__ Vt) {
    __shared__ __align__(16) unsigned short xs[64][128];
    __shared__ __align__(16) unsigned short wt[64][128];
    const int t  = threadIdx.x;
    const int mt = blockIdx.x;
    const int nt = blockIdx.y;

    {
        const int r = t >> 2, qd = t & 3;
        const float* src = &x[(size_t)(mt * 64 + r) * CCH + qd * 32];
        unsigned pk[16];
        #pragma unroll
        for (int i = 0; i < 8; ++i) {
            float4 v = ld4(src + i * 4);
            pk[2 * i]     = pkbf(v.x, v.y);
            pk[2 * i + 1] = pkbf(v.z, v.w);
        }
        #pragma unroll
        for (int g2 = 0; g2 < 4; ++g2) {
            const int gp = (qd * 4 + g2) ^ (r & 7);
            *reinterpret_cast<uint4*>(&xs[r][gp * 8]) =
                make_uint4(pk[4 * g2], pk[4 * g2 + 1], pk[4 * g2 + 2], pk[4 * g2 + 3]);
        }
    }
    {
        const int g  = t >> 4;
        const int j4 = (t & 15) * 4;
        float4 col[8];
        #pragma unroll
        for (int kk = 0; kk < 8; ++kk)
            col[kk] = ld4(&wqkv[(size_t)(g * 8 + kk) * 384 + nt * 64 + j4]);
        const float* c = reinterpret_cast<const float*>(col);
        #pragma unroll
        for (int jj = 0; jj < 4; ++jj) {
            const int j = j4 + jj;
            unsigned a0 = pkbf(c[0 * 4 + jj], c[1 * 4 + jj]);
            unsigned a1 = pkbf(c[2 * 4 + jj], c[3 * 4 + jj]);
            unsigned a2 = pkbf(c[4 * 4 + jj], c[5 * 4 + jj]);
            unsigned a3 = pkbf(c[6 * 4 + jj], c[7 * 4 + jj]);
            *reinterpret_cast<uint4*>(&wt[j][(g ^ (j & 7)) * 8]) = make_uint4(a0, a1, a2, a3);
        }
    }
    __syncthreads();

    const int lane = t & 63, w = t >> 6, q = lane & 15, Lw = lane >> 4;

    short8 qa4[4];
    #pragma unroll
    for (int ks = 0; ks < 4; ++ks)
        qa4[ks] = *reinterpret_cast<const short8*>(
            &xs[w * 16 + q][((Lw + 4 * ks) ^ (q & 7)) * 8]);

    f32x4 acc[4];
    #pragma unroll
    for (int ct = 0; ct < 4; ++ct) acc[ct] = (f32x4)0.f;
    #pragma unroll
    for (int ct = 0; ct < 4; ++ct) {
        const int j = ct * 16 + q;
        #pragma unroll
        for (int ks = 0; ks < 4; ++ks) {
            short8 wb = *reinterpret_cast<const short8*>(
                &wt[j][((Lw + 4 * ks) ^ (j & 7)) * 8]);
            acc[ct] = __builtin_amdgcn_mfma_f32_16x16x32_bf16(qa4[ks], wb, acc[ct], 0, 0, 0);
        }
    }

    const int head  = nt / 3;
    const int which = nt - 3 * head;
    const int gi0 = mt * 64 + w * 16 + Lw * 4;
    const int bb  = gi0 >> 12;
    const int n0  = gi0 & 4095;
    const int bhh = bb * 2 + head;

    if (which == 0) {
        #pragma unroll
        for (int ct = 0; ct < 4; ++ct) {
            const int d = ct * 16 + q;
            #pragma unroll
            for (int r = 0; r < 4; ++r)
                Qb[((size_t)(bhh * NT + n0 + r)) * HD + d] = f2bf(acc[ct][r] * QSCALE_LOG2);
        }
    } else if (which == 1) {
        #pragma unroll
        for (int ct = 0; ct < 4; ++ct) {
            const int d = ct * 16 + q;
            #pragma unroll
            for (int r = 0; r < 4; ++r)
                Kb[((size_t)(bhh * NT + n0 + r)) * HD + d] = f2bf(acc[ct][r]);
        }
    } else {
        #pragma unroll
        for (int ct = 0; ct < 4; ++ct) {
            const int d = ct * 16 + q;
            uint2 u;
            u.x = pkbf(acc[ct][0], acc[ct][1]);
            u.y = pkbf(acc[ct][2], acc[ct][3]);
            *reinterpret_cast<uint2*>(&Vt[((size_t)(bhh * HD + d)) * NT + n0]) = u;
        }
    }
}

// ---------------- Kernel 2: flash attention (r11 structure, bf16 R out) --------
// grid (64, 8). 4 waves x 16 q-rows. S^T = mfma(K,Q): lane owns one q-row.
// exp2-domain softmax; hoisted staging pointers; unroll-by-2 double buffer.
__global__ __launch_bounds__(256) void k_attn(const unsigned short* __restrict__ Qb,
                                              const unsigned short* __restrict__ Kb,
                                              const unsigned short* __restrict__ Vt,
                                              unsigned short* __restrict__ Rb) {
    __shared__ __align__(16) char smem[41984];
    char* Ks0 = smem;
    char* Ks1 = smem + 8192;
    char* Vs0 = smem + 16384;
    char* Vs1 = smem + 24576;
    char* PwA = smem + 32768;      // [4][2304]

    const int t    = threadIdx.x;
    const int lane = t & 63;
    const int w    = t >> 6;
    const int qt   = blockIdx.x;
    const int bh   = blockIdx.y;

    const char* KbT = (const char*)Kb + (size_t)bh * NT * HD * 2;
    const char* VtT = (const char*)Vt + (size_t)bh * HD * NT * 2;

    const int q  = lane & 15;
    const int Lw = lane >> 4;

    short8 qa[2];
    {
        const int qrow = qt * 64 + w * 16 + q;
        const char* qp = (const char*)Qb +
            (((size_t)bh * NT + qrow) * HD + (Lw * 8)) * 2;
        qa[0] = *reinterpret_cast<const short8*>(qp);
        qa[1] = *reinterpret_cast<const short8*>(qp + 64);
    }

    char* Prow = PwA + w * 2304 + q * 144;

    float mrow = -1e30f, lrow = 0.f;
    f32x4 oacc[4];
    #pragma unroll
    for (int i = 0; i < 4; ++i) oacc[i] = (f32x4)0.f;

    const int rc0 = t >> 3;
    const int sp  = t & 7;
    const int rc1 = rc0 + 32;

    const char* kp0 = KbT + rc0 * 128 + (sp ^ (rc0 & 7)) * 16;
    const char* kp1 = KbT + rc1 * 128 + (sp ^ (rc1 & 7)) * 16;
    const char* vp0 = VtT + (size_t)rc0 * 8192 + (sp ^ (rc0 & 7)) * 16;
    const char* vp1 = VtT + (size_t)rc1 * 8192 + (sp ^ (rc1 & 7)) * 16;

    auto gll = [](const char* g, char* l) {
        __builtin_amdgcn_global_load_lds(
            (const __attribute__((address_space(1))) void*)g,
            (__attribute__((address_space(3))) void*)l, 16, 0, 0);
    };
    auto stage = [&](char* KsD, char* VsD) {
        gll(kp0, KsD + t * 16); gll(kp1, KsD + 4096 + t * 16);
        gll(vp0, VsD + t * 16); gll(vp1, VsD + 4096 + t * 16);
        kp0 += 8192; kp1 += 8192; vp0 += 128; vp1 += 128;
    };

    auto compute = [&](const char* KsC, const char* VsC) {
        f32x4 sacc[4];
        #pragma unroll
        for (int ct = 0; ct < 4; ++ct) sacc[ct] = (f32x4)0.f;
        #pragma unroll
        for (int ct = 0; ct < 4; ++ct) {
            const int j = ct * 16 + q;
            #pragma unroll
            for (int ks = 0; ks < 2; ++ks) {
                const int slot = (Lw + 4 * ks) ^ (lane & 7);
                short8 kb = *reinterpret_cast<const short8*>(KsC + j * 128 + slot * 16);
                sacc[ct] = __builtin_amdgcn_mfma_f32_16x16x32_bf16(kb, qa[ks], sacc[ct], 0, 0, 0);
            }
        }
        float mx = -1e30f;
        #pragma unroll
        for (int ct = 0; ct < 4; ++ct)
            #pragma unroll
            for (int r = 0; r < 4; ++r) mx = fmaxf(mx, sacc[ct][r]);
        mx = fmaxf(mx, __shfl_xor(mx, 16));
        mx = fmaxf(mx, __shfl_xor(mx, 32));
        const float mn = fmaxf(mrow, mx);
        const float corr = exp2fast(mrow - mn);
        mrow = mn;
        float e[4][4];
        float sum = 0.f;
        #pragma unroll
        for (int ct = 0; ct < 4; ++ct)
            #pragma unroll
            for (int r = 0; r < 4; ++r) {
                float ev = exp2fast(sacc[ct][r] - mn);
                e[ct][r] = ev;
                sum += ev;
            }
        sum += __shfl_xor(sum, 16);
        sum += __shfl_xor(sum, 32);
        lrow = lrow * corr + sum;
        #pragma unroll
        for (int dt = 0; dt < 4; ++dt) oacc[dt] *= corr;

        #pragma unroll
        for (int ct = 0; ct < 4; ++ct) {
            const int g = 2 * ct + (Lw >> 1);
            uint2 u = make_uint2(pkbf(e[ct][0], e[ct][1]), pkbf(e[ct][2], e[ct][3]));
            *reinterpret_cast<uint2*>(Prow + (((g + 2 * q) & 7) << 4) + ((Lw & 1) << 3)) = u;
        }
        short8 pb[2];
        #pragma unroll
        for (int ks = 0; ks < 2; ++ks)
            pb[ks] = *reinterpret_cast<const short8*>(
                Prow + (((Lw + 4 * ks + 2 * q) & 7) << 4));

        #pragma unroll
        for (int dt = 0; dt < 4; ++dt) {
            const int d = dt * 16 + q;
            #pragma unroll
            for (int ks = 0; ks < 2; ++ks) {
                const int slot = (Lw + 4 * ks) ^ (lane & 7);
                short8 vb = *reinterpret_cast<const short8*>(VsC + d * 128 + slot * 16);
                oacc[dt] = __builtin_amdgcn_mfma_f32_16x16x32_bf16(vb, pb[ks], oacc[dt], 0, 0, 0);
            }
        }
    };

    stage(Ks0, Vs0);
    __syncthreads();
    for (int it = 0; it < 32; ++it) {
        stage(Ks1, Vs1);
        compute(Ks0, Vs0);
        __syncthreads();
        if (it < 31) stage(Ks0, Vs0);
        compute(Ks1, Vs1);
        __syncthreads();
    }

    // epilogue: Rb (bf16) [b*4096+row][h*64 + d]
    const int b = bh >> 1, h = bh & 1;
    const float inv = 1.0f / lrow;
    const int row = qt * 64 + w * 16 + q;
    unsigned short* dst = &Rb[((size_t)(b * NT + row)) * CCH + h * HD];
    #pragma unroll
    for (int dt = 0; dt < 4; ++dt) {
        uint2 u;
        u.x = pkbf(oacc[dt][0] * inv, oacc[dt][1] * inv);
        u.y = pkbf(oacc[dt][2] * inv, oacc[dt][3] * inv);
        *reinterpret_cast<uint2*>(&dst[dt * 16 + Lw * 4]) = u;
    }
}

// ---------------- Kernel 3: output projection, bf16 MFMA ----------------
// Rb bf16 [16384][128] @ wout[128, nt*64..+63] + bias -> out fp32.
// A-frags straight from global (same addressing as k_attn's Qb read);
// w^T staged in LDS with the validated granule swizzle.
__global__ __launch_bounds__(256) void k_out(const unsigned short* __restrict__ Rb,
                                             const float* __restrict__ wout,
                                             const float* __restrict__ bout,
                                             float* __restrict__ out) {
    __shared__ __align__(16) unsigned short wt[64][128];
    const int t  = threadIdx.x;
    const int mt = blockIdx.x;
    const int nt = blockIdx.y;

    {
        const int g  = t >> 4;
        const int j4 = (t & 15) * 4;
        float4 col[8];
        #pragma unroll
        for (int kk = 0; kk < 8; ++kk)
            col[kk] = ld4(&wout[(size_t)(g * 8 + kk) * CCH + nt * 64 + j4]);
        const float* c = reinterpret_cast<const float*>(col);
        #pragma unroll
        for (int jj = 0; jj < 4; ++jj) {
            const int j = j4 + jj;
            unsigned a0 = pkbf(c[0 * 4 + jj], c[1 * 4 + jj]);
            unsigned a1 = pkbf(c[2 * 4 + jj], c[3 * 4 + jj]);
            unsigned a2 = pkbf(c[4 * 4 + jj], c[5 * 4 + jj]);
            unsigned a3 = pkbf(c[6 * 4 + jj], c[7 * 4 + jj]);
            *reinterpret_cast<uint4*>(&wt[j][(g ^ (j & 7)) * 8]) = make_uint4(a0, a1, a2, a3);
        }
    }

    const int lane = t & 63, w = t >> 6, q = lane & 15, Lw = lane >> 4;

    // A-frags from global: row = mt*64 + w*16 + q, k = Lw*8 + i + 32ks
    short8 ra[4];
    {
        const char* rp = (const char*)Rb +
            (((size_t)(mt * 64 + w * 16 + q)) * CCH + Lw * 8) * 2;
        #pragma unroll
        for (int ks = 0; ks < 4; ++ks)
            ra[ks] = *reinterpret_cast<const short8*>(rp + ks * 64);
    }
    __syncthreads();

    f32x4 acc[4];
    #pragma unroll
    for (int ct = 0; ct < 4; ++ct) acc[ct] = (f32x4)0.f;
    #pragma unroll
    for (int ct = 0; ct < 4; ++ct) {
        const int j = ct * 16 + q;
        #pragma unroll
        for (int ks = 0; ks < 4; ++ks) {
            short8 wb = *reinterpret_cast<const short8*>(
                &wt[j][((Lw + 4 * ks) ^ (j & 7)) * 8]);
            acc[ct] = __builtin_amdgcn_mfma_f32_16x16x32_bf16(ra[ks], wb, acc[ct], 0, 0, 0);
        }
    }

    // epilogue: out[mt*64 + w*16 + Lw*4 + r][nt*64 + ct*16 + q] fp32 + bias
    const int row0 = mt * 64 + w * 16 + Lw * 4;
    #pragma unroll
    for (int ct = 0; ct < 4; ++ct) {
        const int col = nt * 64 + ct * 16 + q;
        const float bias = bout[col];
        #pragma unroll
        for (int r = 0; r < 4; ++r)
            out[(size_t)(row0 + r) * CCH + col] = acc[ct][r] + bias;
    }
}

extern "C" void kernel_launch(void* const* d_in, const int* in_sizes, int n_in,
                              void* d_out, int out_size, void* d_ws, size_t ws_size,
                              hipStream_t stream) {
    const float* x    = (const float*)d_in[0];
    const float* wqkv = (const float*)d_in[1];
    const float* wout = (const float*)d_in[2];
    const float* bout = (const float*)d_in[3];
    float* out = (float*)d_out;

    // workspace: Qb/Kb/Vt bf16 (4MB each), Rb bf16 (4MB) = 16MB
    unsigned short* Qb = (unsigned short*)d_ws;
    unsigned short* Kb = Qb + 2097152;
    unsigned short* Vt = Kb + 2097152;
    unsigned short* Rb = Vt + 2097152;

    k_qkv<<<dim3(256, 6), 256, 0, stream>>>(x, wqkv, Qb, Kb, Vt);
    k_attn<<<dim3(64, 8), 256, 0, stream>>>(Qb, Kb, Vt, Rb);
    k_out<<<dim3(256, 2), 256, 0, stream>>>(Rb, wout, bout, out);
}